// Round 2
// baseline (1380.165 us; speedup 1.0000x reference)
//
#include <hip/hip_runtime.h>
#include <hip/hip_bf16.h>
#include <stdint.h>

#define BB   256
#define DD   64
#define LLEN 50
#define PDIM 10
#define CDIM 8
#define NITEMS 1000000
#define TOPK 20
#define TI   128          // items per LDS tile
#define SCORE_THREADS 512

typedef short v8s __attribute__((ext_vector_type(8)));   // 8 bf16 (4 VGPR)
typedef float v4f __attribute__((ext_vector_type(4)));   // MFMA acc

// float -> bf16 bits, round-to-nearest-even (no NaN inputs here)
__device__ __forceinline__ uint32_t f2bf_rne(float f) {
    uint32_t u = __float_as_uint(f);
    return (u + 0x7FFFu + ((u >> 16) & 1u)) >> 16;
}

// ---- sortable key: larger key == better (higher score, then lower index) ----
__device__ __forceinline__ unsigned long long pack_key(float s, unsigned n) {
    unsigned sb = __float_as_uint(s);
    sb = (sb & 0x80000000u) ? ~sb : (sb | 0x80000000u);
    return ((unsigned long long)sb << 32) | (unsigned)(~n);
}

__device__ __forceinline__ void insert20(unsigned long long (&best)[TOPK],
                                         unsigned long long key) {
    unsigned long long prev = ~0ull;
    #pragma unroll
    for (int j = 0; j < TOPK; ++j) {
        unsigned long long cur = best[j];
        best[j] = (key > cur) ? ((key > prev) ? prev : key) : cur;
        prev = cur;
    }
}

// guarded insert with float threshold cache
__device__ __forceinline__ void try_insert(unsigned long long (&best)[TOPK],
                                           float& thr, float s, unsigned idx) {
    if (s < thr) return;
    unsigned long long key = pack_key(s, idx);
    if (key <= best[TOPK - 1]) return;
    insert20(best, key);
    unsigned sb = (unsigned)(best[TOPK - 1] >> 32);
    if (sb != 0u) {   // list full of real keys -> tighten threshold
        unsigned orig = (sb & 0x80000000u) ? (sb & 0x7FFFFFFFu) : ~sb;
        thr = __uint_as_float(orig);
    }
}

// 64-bit shuffle via two 32-bit shuffles (guaranteed-available path)
__device__ __forceinline__ unsigned long long shfl_xor_u64(unsigned long long x, int m) {
    unsigned lo = (unsigned)x, hi = (unsigned)(x >> 32);
    lo = __shfl_xor(lo, m);
    hi = __shfl_xor(hi, m);
    return ((unsigned long long)hi << 32) | lo;
}

// ================= Phase A: user tower -> bf16 hi/lo user vectors ===========
__global__ __launch_bounds__(64) void user_kernel(
        const int* __restrict__ profile,      // [B,10]
        const int* __restrict__ context,      // [B,50,8]
        const int* __restrict__ item_idx,     // [B,50]
        const float* __restrict__ iv,         // [N,64]
        const float* __restrict__ Wp,         // [10,64]
        const float* __restrict__ Wc,         // [8,64]
        const float* __restrict__ Wu,         // [64,64]
        const float* __restrict__ bu,         // [64]
        ushort* __restrict__ uhi,             // [256,64] bf16 bits
        ushort* __restrict__ ulo)             // [256,64] bf16 bits
{
    const int b = blockIdx.x;
    const int d = threadIdx.x;   // 0..63

    float p = 0.f;
    #pragma unroll
    for (int j = 0; j < PDIM; ++j)
        p += (float)profile[b * PDIM + j] * Wp[j * DD + d];

    float c = 0.f;
    #pragma unroll
    for (int j = 0; j < CDIM; ++j) {
        int s = 0;
        for (int l = 0; l < LLEN; ++l)
            s += context[(b * LLEN + l) * CDIM + j];
        c += ((float)s * (1.f / (float)LLEN)) * Wc[j * DD + d];
    }

    float si = 0.f;
    for (int l = 0; l < LLEN; ++l) {
        size_t n = (size_t)item_idx[b * LLEN + l];
        si += iv[n * DD + d];
    }
    si *= (1.f / (float)LLEN);

    __shared__ float sh[DD];
    sh[d] = p + c + si;
    __syncthreads();

    float acc = bu[d];
    #pragma unroll
    for (int dd = 0; dd < DD; ++dd)
        acc = fmaf(sh[dd], Wu[dd * DD + d], acc);

    float val = tanhf(acc);
    uint32_t hb = f2bf_rne(val);
    float hf = __uint_as_float(hb << 16);
    uint32_t lb = f2bf_rne(val - hf);
    uhi[b * DD + d] = (ushort)hb;
    ulo[b * DD + d] = (ushort)lb;
}

// ============ Phase B: MFMA scoring + fused per-thread top-20 ================
// Block = 512 threads = 8 waves. Wave w owns users [32w, 32w+32) as two
// 16-user MFMA N-tiles. Items stream through LDS in fragment-linear layout:
// for (msub,ks): lane l reads 16B at block_base + 16*l (conflict-free).
__global__ __launch_bounds__(SCORE_THREADS) void score_kernel(
        const float*  __restrict__ iv,         // [N,64]
        const ushort* __restrict__ uhi,        // [256,64]
        const ushort* __restrict__ ulo,        // [256,64]
        unsigned long long* __restrict__ part, // [user][nblk][20]
        int chunk, int nblk)
{
    // [buf][hi=0/lo=1][ (msub*2+ks)*64 + slot ][4 u32]  -> 2*2*16KB = 64 KB
    __shared__ uint32_t lds[2][2][4096];

    const int t    = threadIdx.x;
    const int w    = t >> 6;
    const int lane = t & 63;
    const int blk  = blockIdx.x;
    const long base = (long)blk * (long)chunk;

    // ---- user B-fragments in registers ----
    // B frag (K=32): col = lane&15 (user), k = 32*ks + 8*(lane>>4) + e
    const int ua = 32 * w + (lane & 15);
    const int ub = ua + 16;
    v8s uhA[2], ulA[2], uhB[2], ulB[2];
    #pragma unroll
    for (int ks = 0; ks < 2; ++ks) {
        int kk = 32 * ks + 8 * (lane >> 4);
        uhA[ks] = *(const v8s*)(uhi + ua * DD + kk);
        ulA[ks] = *(const v8s*)(ulo + ua * DD + kk);
        uhB[ks] = *(const v8s*)(uhi + ub * DD + kk);
        ulB[ks] = *(const v8s*)(ulo + ub * DD + kk);
    }

    unsigned long long bestA[TOPK], bestB[TOPK];
    #pragma unroll
    for (int k = 0; k < TOPK; ++k) { bestA[k] = 0ull; bestB[k] = 0ull; }
    float thrA = -INFINITY, thrB = -INFINITY;

    long nitems_blk = (long)NITEMS - base;
    if (nitems_blk > chunk) nitems_blk = chunk;
    const int ntiles = (int)((nitems_blk + TI - 1) / TI);

    float4 ld[2][2];   // in-flight staging regs (2 float4 per r)

    // staging map: f8 = r*512 + t ; item = f8>>3 (0..127); k0 = (f8&7)*8
    auto stage_issue = [&](long tb) {
        #pragma unroll
        for (int r = 0; r < 2; ++r) {
            int f8 = r * 512 + t;
            long item = base + tb + (f8 >> 3);
            if (item < (long)NITEMS) {
                const float4* src =
                    (const float4*)(iv + (size_t)item * DD + (f8 & 7) * 8);
                ld[r][0] = src[0];
                ld[r][1] = src[1];
            } else {
                ld[r][0] = make_float4(0.f, 0.f, 0.f, 0.f);
                ld[r][1] = make_float4(0.f, 0.f, 0.f, 0.f);
            }
        }
    };
    auto stage_write = [&](int buf) {
        #pragma unroll
        for (int r = 0; r < 2; ++r) {
            int f8 = r * 512 + t;
            int item = f8 >> 3, k7 = f8 & 7;
            int dst = (((item >> 4) * 2 + (k7 >> 2)) * 64 +
                       (item & 15) + 16 * (k7 & 3)) * 4;
            float fv[8] = {ld[r][0].x, ld[r][0].y, ld[r][0].z, ld[r][0].w,
                           ld[r][1].x, ld[r][1].y, ld[r][1].z, ld[r][1].w};
            uint32_t hw[4], lw[4];
            #pragma unroll
            for (int j = 0; j < 4; ++j) {
                uint32_t h0 = f2bf_rne(fv[2 * j]);
                uint32_t h1 = f2bf_rne(fv[2 * j + 1]);
                float hf0 = __uint_as_float(h0 << 16);
                float hf1 = __uint_as_float(h1 << 16);
                uint32_t l0 = f2bf_rne(fv[2 * j] - hf0);
                uint32_t l1 = f2bf_rne(fv[2 * j + 1] - hf1);
                hw[j] = h0 | (h1 << 16);
                lw[j] = l0 | (l1 << 16);
            }
            *(uint4*)&lds[buf][0][dst] = make_uint4(hw[0], hw[1], hw[2], hw[3]);
            *(uint4*)&lds[buf][1][dst] = make_uint4(lw[0], lw[1], lw[2], lw[3]);
        }
    };

    stage_issue(0);
    stage_write(0);
    __syncthreads();

    for (int tt = 0; tt < ntiles; ++tt) {
        const int buf = tt & 1;
        if (tt + 1 < ntiles) stage_issue((long)(tt + 1) * TI);  // hide HBM

        const long ibase = base + (long)tt * TI;
        #pragma unroll
        for (int ms = 0; ms < 8; ++ms) {
            v4f accA = {0.f, 0.f, 0.f, 0.f};
            v4f accB = {0.f, 0.f, 0.f, 0.f};
            #pragma unroll
            for (int ks = 0; ks < 2; ++ks) {
                int bidx = ((ms * 2 + ks) * 64 + lane) * 4;
                v8s ah = *(const v8s*)&lds[buf][0][bidx];
                v8s al = *(const v8s*)&lds[buf][1][bidx];
                accA = __builtin_amdgcn_mfma_f32_16x16x32_bf16(ah, uhA[ks], accA, 0, 0, 0);
                accB = __builtin_amdgcn_mfma_f32_16x16x32_bf16(ah, uhB[ks], accB, 0, 0, 0);
                accA = __builtin_amdgcn_mfma_f32_16x16x32_bf16(al, uhA[ks], accA, 0, 0, 0);
                accB = __builtin_amdgcn_mfma_f32_16x16x32_bf16(al, uhB[ks], accB, 0, 0, 0);
                accA = __builtin_amdgcn_mfma_f32_16x16x32_bf16(ah, ulA[ks], accA, 0, 0, 0);
                accB = __builtin_amdgcn_mfma_f32_16x16x32_bf16(ah, ulB[ks], accB, 0, 0, 0);
            }
            // D layout: col = lane&15 (user), row = (lane>>4)*4 + reg (item)
            long irow = ibase + ms * 16 + (lane >> 4) * 4;
            #pragma unroll
            for (int r = 0; r < 4; ++r) {
                long idx = irow + r;
                if (idx < (long)NITEMS) {
                    try_insert(bestA, thrA, accA[r], (unsigned)idx);
                    try_insert(bestB, thrB, accB[r], (unsigned)idx);
                }
            }
        }

        if (tt + 1 < ntiles) stage_write(buf ^ 1);
        __syncthreads();
    }

    // ---- butterfly-merge the 4 lane-groups sharing each user column ----
    #pragma unroll
    for (int step = 16; step <= 32; step <<= 1) {
        #pragma unroll
        for (int k = 0; k < TOPK; ++k) {
            unsigned long long oA = shfl_xor_u64(bestA[k], step);
            if (oA > bestA[TOPK - 1]) insert20(bestA, oA);
        }
        #pragma unroll
        for (int k = 0; k < TOPK; ++k) {
            unsigned long long oB = shfl_xor_u64(bestB[k], step);
            if (oB > bestB[TOPK - 1]) insert20(bestB, oB);
        }
    }

    if ((lane >> 4) == 0) {
        unsigned long long* dA = part + ((size_t)ua * nblk + blk) * TOPK;
        unsigned long long* dB = part + ((size_t)ub * nblk + blk) * TOPK;
        #pragma unroll
        for (int k = 0; k < TOPK; ++k) { dA[k] = bestA[k]; dB[k] = bestB[k]; }
    }
}

// ================= Phase C: merge per-user partials -> top-20 indices ========
__global__ __launch_bounds__(256) void merge_kernel(
        const unsigned long long* __restrict__ part, // [B][nblk][20]
        int* __restrict__ out,                       // [B,20]
        int nblk)
{
    const int b = blockIdx.x;
    const int t = threadIdx.x;
    const unsigned long long* src = part + (size_t)b * nblk * TOPK;
    const int total = nblk * TOPK;

    unsigned long long best[TOPK];
    #pragma unroll
    for (int k = 0; k < TOPK; ++k) best[k] = 0ull;

    for (int i = t; i < total; i += 256) {
        unsigned long long key = src[i];
        if (key > best[TOPK - 1]) insert20(best, key);
    }

    __shared__ unsigned long long cand[256 * TOPK];
    __shared__ unsigned long long wmax[4];
    #pragma unroll
    for (int k = 0; k < TOPK; ++k) cand[t * TOPK + k] = best[k];
    __syncthreads();

    int own = 0;
    for (int round = 0; round < TOPK; ++round) {
        unsigned long long v = (own < TOPK) ? cand[t * TOPK + own] : 0ull;
        unsigned long long m = v;
        #pragma unroll
        for (int s = 32; s > 0; s >>= 1) {
            unsigned long long o = shfl_xor_u64(m, s);
            m = (o > m) ? o : m;
        }
        if ((t & 63) == 0) wmax[t >> 6] = m;
        __syncthreads();
        unsigned long long g01 = (wmax[0] > wmax[1]) ? wmax[0] : wmax[1];
        unsigned long long g23 = (wmax[2] > wmax[3]) ? wmax[2] : wmax[3];
        unsigned long long g = (g01 > g23) ? g01 : g23;
        if (v == g && v != 0ull) own++;
        if (t == 0) out[b * TOPK + round] = (int)(~(unsigned)(g & 0xFFFFFFFFull));
        __syncthreads();
    }
}

// =============================================================================
extern "C" void kernel_launch(void* const* d_in, const int* in_sizes, int n_in,
                              void* d_out, int out_size, void* d_ws, size_t ws_size,
                              hipStream_t stream) {
    const int*   profile  = (const int*)d_in[0];
    const int*   context  = (const int*)d_in[1];
    const int*   item_idx = (const int*)d_in[2];
    const float* iv       = (const float*)d_in[3];
    const float* Wp       = (const float*)d_in[4];
    const float* Wc       = (const float*)d_in[5];
    const float* Wu       = (const float*)d_in[6];
    const float* bu       = (const float*)d_in[7];

    ushort* uhi = (ushort*)d_ws;                                   // 32 KB
    ushort* ulo = (ushort*)((char*)d_ws + 32768);                  // 32 KB
    const size_t off_part = 65536;
    unsigned long long* part =
        (unsigned long long*)((char*)d_ws + off_part);

    size_t avail = (ws_size > off_part) ? (ws_size - off_part) : 0;
    long maxblk = (long)(avail / ((size_t)BB * TOPK * 8));
    if (maxblk < 1) maxblk = 1;
    int chunk = 1024;                       // multiple of TI
    int nblk = (NITEMS + chunk - 1) / chunk;
    if (nblk > maxblk) {
        long c = (NITEMS + maxblk - 1) / maxblk;
        chunk = (int)((c + TI - 1) / TI) * TI;
        nblk = (NITEMS + chunk - 1) / chunk;
    }

    user_kernel<<<BB, DD, 0, stream>>>(profile, context, item_idx, iv,
                                       Wp, Wc, Wu, bu, uhi, ulo);
    score_kernel<<<nblk, SCORE_THREADS, 0, stream>>>(iv, uhi, ulo, part,
                                                     chunk, nblk);
    merge_kernel<<<BB, 256, 0, stream>>>(part, (int*)d_out, nblk);
}

// Round 4
// 1173.462 us; speedup vs baseline: 1.1761x; 1.1761x over previous
//
#include <hip/hip_runtime.h>
#include <hip/hip_bf16.h>
#include <stdint.h>

#define BB   256
#define DD   64
#define LLEN 50
#define PDIM 10
#define CDIM 8
#define NITEMS 1000000
#define TOPK 20
#define CAND 32           // approx candidates kept per user before exact rescore
#define TI   128          // items per LDS tile
#define SCORE_THREADS 512

typedef short v8s __attribute__((ext_vector_type(8)));   // 8 bf16 (4 VGPR)
typedef float v4f __attribute__((ext_vector_type(4)));   // MFMA acc

// float -> bf16 bits, round-to-nearest-even
__device__ __forceinline__ uint32_t f2bf_rne(float f) {
    uint32_t u = __float_as_uint(f);
    return (u + 0x7FFFu + ((u >> 16) & 1u)) >> 16;
}

// ---- sortable key: larger key == better (higher score, then lower index) ----
__device__ __forceinline__ unsigned long long pack_key(float s, unsigned n) {
    unsigned sb = __float_as_uint(s);
    sb = (sb & 0x80000000u) ? ~sb : (sb | 0x80000000u);
    return ((unsigned long long)sb << 32) | (unsigned)(~n);
}

__device__ __forceinline__ float unpack_score(unsigned sb) {
    unsigned orig = (sb & 0x80000000u) ? (sb & 0x7FFFFFFFu) : ~sb;
    return __uint_as_float(orig);
}

__device__ __forceinline__ void insert20(unsigned long long (&best)[TOPK],
                                         unsigned long long key) {
    unsigned long long prev = ~0ull;
    #pragma unroll
    for (int j = 0; j < TOPK; ++j) {
        unsigned long long cur = best[j];
        best[j] = (key > cur) ? ((key > prev) ? prev : key) : cur;
        prev = cur;
    }
}

__device__ __forceinline__ unsigned long long shfl_xor_u64(unsigned long long x, int m) {
    unsigned lo = (unsigned)x, hi = (unsigned)(x >> 32);
    lo = __shfl_xor(lo, m);
    hi = __shfl_xor(hi, m);
    return ((unsigned long long)hi << 32) | lo;
}

// ================= Phase A: user tower -> fp32 + bf16 hi/lo user vectors =====
__global__ __launch_bounds__(64) void user_kernel(
        const int* __restrict__ profile,      // [B,10]
        const int* __restrict__ context,      // [B,50,8]
        const int* __restrict__ item_idx,     // [B,50]
        const float* __restrict__ iv,         // [N,64]
        const float* __restrict__ Wp,         // [10,64]
        const float* __restrict__ Wc,         // [8,64]
        const float* __restrict__ Wu,         // [64,64]
        const float* __restrict__ bu,         // [64]
        ushort* __restrict__ uhi,             // [256,64] bf16 bits
        ushort* __restrict__ ulo,             // [256,64] bf16 bits
        float*  __restrict__ ufp)             // [256,64] fp32
{
    const int b = blockIdx.x;
    const int d = threadIdx.x;   // 0..63

    float p = 0.f;
    #pragma unroll
    for (int j = 0; j < PDIM; ++j)
        p += (float)profile[b * PDIM + j] * Wp[j * DD + d];

    float c = 0.f;
    #pragma unroll
    for (int j = 0; j < CDIM; ++j) {
        int s = 0;
        for (int l = 0; l < LLEN; ++l)
            s += context[(b * LLEN + l) * CDIM + j];
        c += ((float)s * (1.f / (float)LLEN)) * Wc[j * DD + d];
    }

    float si = 0.f;
    for (int l = 0; l < LLEN; ++l) {
        size_t n = (size_t)item_idx[b * LLEN + l];
        si += iv[n * DD + d];
    }
    si *= (1.f / (float)LLEN);

    __shared__ float sh[DD];
    sh[d] = p + c + si;
    __syncthreads();

    float acc = bu[d];
    #pragma unroll
    for (int dd = 0; dd < DD; ++dd)
        acc = fmaf(sh[dd], Wu[dd * DD + d], acc);

    float val = tanhf(acc);
    ufp[b * DD + d] = val;
    uint32_t hb = f2bf_rne(val);
    float hf = __uint_as_float(hb << 16);
    uint32_t lb = f2bf_rne(val - hf);
    uhi[b * DD + d] = (ushort)hb;
    ulo[b * DD + d] = (ushort)lb;
}

// ============ Phase B: MFMA scoring + fused per-thread top-20 ================
// 512 threads = 8 waves. Wave w owns users [32w,32w+32) (two 16-user B-tiles).
// LDS frag layout (VERIFIED R2): frag f=2*ms+ks at words [f*256,+256),
// word = f*256 + 4*slot + j, slot=(item&15)+16*q, word j = dims 32ks+8q+{2j,2j+1}.
// Staging: wave w fills frags (ms=w, ks=0/1): lane l -> item 16w+(l&15),
// q=l>>4 -> slot==l -> 16B write at frag_base+16*l (2-way bank = free).
__global__ __launch_bounds__(SCORE_THREADS, 2) void score_kernel(
        const float*  __restrict__ iv,         // [N,64]
        const ushort* __restrict__ uhi,        // [256,64]
        const ushort* __restrict__ ulo,        // [256,64]
        unsigned long long* __restrict__ part, // [user][nblk][20]
        int chunk, int nblk)
{
    __shared__ uint32_t lds[2][2][4096];   // [buf][hi/lo][16KB] = 64 KB

    const int t    = threadIdx.x;
    const int w    = t >> 6;
    const int lane = t & 63;
    const int blk  = blockIdx.x;
    const long base = (long)blk * (long)chunk;

    // ---- user B-fragments (col=lane&15=user, k=32ks+8*(lane>>4)+e) ----
    const int ua = 32 * w + (lane & 15);
    const int ub = ua + 16;
    v8s uhA[2], ulA[2], uhB[2], ulB[2];
    #pragma unroll
    for (int ks = 0; ks < 2; ++ks) {
        int kk = 32 * ks + 8 * (lane >> 4);
        uhA[ks] = *(const v8s*)(uhi + ua * DD + kk);
        ulA[ks] = *(const v8s*)(ulo + ua * DD + kk);
        uhB[ks] = *(const v8s*)(uhi + ub * DD + kk);
        ulB[ks] = *(const v8s*)(ulo + ub * DD + kk);
    }

    unsigned long long bestA[TOPK], bestB[TOPK];
    #pragma unroll
    for (int k = 0; k < TOPK; ++k) { bestA[k] = 0ull; bestB[k] = 0ull; }
    float thrA = -INFINITY, thrB = -INFINITY;

    long nitems_blk = (long)NITEMS - base;
    if (nitems_blk > chunk) nitems_blk = chunk;
    const int ntiles = (int)((nitems_blk + TI - 1) / TI);

    // ---- staging regs: item 16w+(l&15), dims 32ks+8*(l>>4)+0..7 ----
    float4 st[4];
    const long my_item_off = 16 * w + (lane & 15);
    const int  my_dim0     = 8 * (lane >> 4);

    auto stage_issue = [&](long tb) {
        long item = base + tb + my_item_off;
        if (item < (long)NITEMS) {
            const float* rowp = iv + (size_t)item * DD + my_dim0;
            #pragma unroll
            for (int ks = 0; ks < 2; ++ks) {
                const float4* p = (const float4*)(rowp + 32 * ks);
                st[2 * ks]     = p[0];
                st[2 * ks + 1] = p[1];
            }
        } else {
            #pragma unroll
            for (int r = 0; r < 4; ++r) st[r] = make_float4(0.f, 0.f, 0.f, 0.f);
        }
    };
    auto stage_write = [&](int buf) {
        #pragma unroll
        for (int ks = 0; ks < 2; ++ks) {
            float f[8] = {st[2*ks].x, st[2*ks].y, st[2*ks].z, st[2*ks].w,
                          st[2*ks+1].x, st[2*ks+1].y, st[2*ks+1].z, st[2*ks+1].w};
            uint32_t hw[4], lw[4];
            #pragma unroll
            for (int j = 0; j < 4; ++j) {
                uint32_t h0 = f2bf_rne(f[2 * j]);        // RNE split (R2-verified)
                uint32_t h1 = f2bf_rne(f[2 * j + 1]);
                float hf0 = __uint_as_float(h0 << 16);
                float hf1 = __uint_as_float(h1 << 16);
                uint32_t l0 = f2bf_rne(f[2 * j]     - hf0);
                uint32_t l1 = f2bf_rne(f[2 * j + 1] - hf1);
                hw[j] = h0 | (h1 << 16);
                lw[j] = l0 | (l1 << 16);
            }
            int fr = 2 * w + ks;
            int wd = fr * 256 + 4 * lane;
            *(uint4*)&lds[buf][0][wd] = make_uint4(hw[0], hw[1], hw[2], hw[3]);
            *(uint4*)&lds[buf][1][wd] = make_uint4(lw[0], lw[1], lw[2], lw[3]);
        }
    };

    auto try_ins = [&](unsigned long long (&best)[TOPK], float& thr,
                       float s, long idx) {
        if (idx < (long)NITEMS) {
            unsigned long long key = pack_key(s, (unsigned)idx);
            if (key > best[TOPK - 1]) {
                insert20(best, key);
                unsigned sb = (unsigned)(best[TOPK - 1] >> 32);
                if (sb) thr = unpack_score(sb);
            }
        }
    };

    stage_issue(0);
    stage_write(0);
    __syncthreads();

    for (int tt = 0; tt < ntiles; ++tt) {
        const int buf = tt & 1;
        if (tt + 1 < ntiles) stage_issue((long)(tt + 1) * TI);

        // cross-lane safe bound: min over 4 user-owning lanes of 5th-best.
        // (their 4x5 = 20 kept items all score >= tau -> union top-20 >= tau,
        //  so any s < tau can never reach the user's final top-20.)
        unsigned sbA = (unsigned)(bestA[4] >> 32);
        unsigned sbB = (unsigned)(bestB[4] >> 32);
        float tauA = sbA ? unpack_score(sbA) : -INFINITY;
        float tauB = sbB ? unpack_score(sbB) : -INFINITY;
        tauA = fminf(tauA, __shfl_xor(tauA, 16));
        tauA = fminf(tauA, __shfl_xor(tauA, 32));
        tauB = fminf(tauB, __shfl_xor(tauB, 16));
        tauB = fminf(tauB, __shfl_xor(tauB, 32));

        const long ibase = base + (long)tt * TI;
        #pragma unroll
        for (int ms = 0; ms < 8; ++ms) {
            v4f accA = {0.f, 0.f, 0.f, 0.f};
            v4f accB = {0.f, 0.f, 0.f, 0.f};
            #pragma unroll
            for (int ks = 0; ks < 2; ++ks) {
                int bidx = ((ms * 2 + ks) * 64 + lane) * 4;
                v8s ah = *(const v8s*)&lds[buf][0][bidx];
                v8s al = *(const v8s*)&lds[buf][1][bidx];
                accA = __builtin_amdgcn_mfma_f32_16x16x32_bf16(ah, uhA[ks], accA, 0, 0, 0);
                accB = __builtin_amdgcn_mfma_f32_16x16x32_bf16(ah, uhB[ks], accB, 0, 0, 0);
                accA = __builtin_amdgcn_mfma_f32_16x16x32_bf16(al, uhA[ks], accA, 0, 0, 0);
                accB = __builtin_amdgcn_mfma_f32_16x16x32_bf16(al, uhB[ks], accB, 0, 0, 0);
                accA = __builtin_amdgcn_mfma_f32_16x16x32_bf16(ah, ulA[ks], accA, 0, 0, 0);
                accB = __builtin_amdgcn_mfma_f32_16x16x32_bf16(ah, ulB[ks], accB, 0, 0, 0);
            }
            // D layout: col=lane&15 (user), row=(lane>>4)*4+reg (item)
            long irow = ibase + ms * 16 + (lane >> 4) * 4;

            float gA = fmaxf(thrA, tauA);
            float mA = fmaxf(fmaxf(accA[0], accA[1]), fmaxf(accA[2], accA[3]));
            if (mA >= gA) {
                #pragma unroll
                for (int r = 0; r < 4; ++r)
                    if (accA[r] >= gA) try_ins(bestA, thrA, accA[r], irow + r);
            }
            float gB = fmaxf(thrB, tauB);
            float mB = fmaxf(fmaxf(accB[0], accB[1]), fmaxf(accB[2], accB[3]));
            if (mB >= gB) {
                #pragma unroll
                for (int r = 0; r < 4; ++r)
                    if (accB[r] >= gB) try_ins(bestB, thrB, accB[r], irow + r);
            }
        }

        if (tt + 1 < ntiles) stage_write(buf ^ 1);
        __syncthreads();
    }

    // ---- butterfly-merge the 4 lane-groups sharing each user column ----
    #pragma unroll
    for (int step = 16; step <= 32; step <<= 1) {
        #pragma unroll
        for (int k = 0; k < TOPK; ++k) {
            unsigned long long oA = shfl_xor_u64(bestA[k], step);
            if (oA > bestA[TOPK - 1]) insert20(bestA, oA);
        }
        #pragma unroll
        for (int k = 0; k < TOPK; ++k) {
            unsigned long long oB = shfl_xor_u64(bestB[k], step);
            if (oB > bestB[TOPK - 1]) insert20(bestB, oB);
        }
    }

    if ((lane >> 4) == 0) {
        unsigned long long* dA = part + ((size_t)ua * nblk + blk) * TOPK;
        unsigned long long* dB = part + ((size_t)ub * nblk + blk) * TOPK;
        #pragma unroll
        for (int k = 0; k < TOPK; ++k) { dA[k] = bestA[k]; dB[k] = bestB[k]; }
    }
}

// ========== Phase C: merge partials -> approx top-32 candidate indices =======
__global__ __launch_bounds__(256) void merge_kernel(
        const unsigned long long* __restrict__ part, // [B][nblk][20]
        int* __restrict__ cand,                      // [B,32]
        int nblk)
{
    const int b = blockIdx.x;
    const int t = threadIdx.x;
    const unsigned long long* src = part + (size_t)b * nblk * TOPK;
    const int total = nblk * TOPK;

    unsigned long long best[TOPK];
    #pragma unroll
    for (int k = 0; k < TOPK; ++k) best[k] = 0ull;

    for (int i = t; i < total; i += 256) {
        unsigned long long key = src[i];
        if (key > best[TOPK - 1]) insert20(best, key);
    }

    __shared__ unsigned long long lcand[256 * TOPK];
    __shared__ unsigned long long wmax[4];
    #pragma unroll
    for (int k = 0; k < TOPK; ++k) lcand[t * TOPK + k] = best[k];
    __syncthreads();

    int own = 0;
    for (int round = 0; round < CAND; ++round) {
        unsigned long long v = (own < TOPK) ? lcand[t * TOPK + own] : 0ull;
        unsigned long long m = v;
        #pragma unroll
        for (int s = 32; s > 0; s >>= 1) {
            unsigned long long o = shfl_xor_u64(m, s);
            m = (o > m) ? o : m;
        }
        if ((t & 63) == 0) wmax[t >> 6] = m;
        __syncthreads();
        unsigned long long g01 = (wmax[0] > wmax[1]) ? wmax[0] : wmax[1];
        unsigned long long g23 = (wmax[2] > wmax[3]) ? wmax[2] : wmax[3];
        unsigned long long g = (g01 > g23) ? g01 : g23;
        if (v == g && v != 0ull) own++;
        if (t == 0)
            cand[b * CAND + round] = g ? (int)(~(unsigned)(g & 0xFFFFFFFFull)) : 0;
        __syncthreads();
    }
}

// ========== Phase D: exact fp32 rescore of 32 candidates -> top-20 ===========
__global__ __launch_bounds__(64) void rescore_kernel(
        const float* __restrict__ iv,    // [N,64]
        const float* __restrict__ ufp,   // [256,64]
        const int*   __restrict__ cand,  // [256,32]
        int* __restrict__ out)           // [256,20]
{
    const int b    = blockIdx.x;
    const int lane = threadIdx.x;   // 0..63

    const float u = ufp[b * DD + lane];
    float myscore = 0.f;
    int   myidx   = 0;

    for (int c = 0; c < CAND; ++c) {
        int idx = cand[b * CAND + c];
        float x = iv[(size_t)idx * DD + lane];
        float p = u * x;
        #pragma unroll
        for (int s = 32; s > 0; s >>= 1) p += __shfl_xor(p, s);
        if (lane == c) { myscore = p; myidx = idx; }
    }

    unsigned long long key =
        (lane < CAND) ? pack_key(myscore, (unsigned)myidx) : 0ull;

    for (int round = 0; round < TOPK; ++round) {
        unsigned long long m = key;
        #pragma unroll
        for (int s = 32; s > 0; s >>= 1) {
            unsigned long long o = shfl_xor_u64(m, s);
            m = (o > m) ? o : m;
        }
        if (key == m && key != 0ull) key = 0ull;   // keys unique -> one winner
        if (lane == 0)
            out[b * TOPK + round] = (int)(~(unsigned)(m & 0xFFFFFFFFull));
    }
}

// =============================================================================
extern "C" void kernel_launch(void* const* d_in, const int* in_sizes, int n_in,
                              void* d_out, int out_size, void* d_ws, size_t ws_size,
                              hipStream_t stream) {
    const int*   profile  = (const int*)d_in[0];
    const int*   context  = (const int*)d_in[1];
    const int*   item_idx = (const int*)d_in[2];
    const float* iv       = (const float*)d_in[3];
    const float* Wp       = (const float*)d_in[4];
    const float* Wc       = (const float*)d_in[5];
    const float* Wu       = (const float*)d_in[6];
    const float* bu       = (const float*)d_in[7];

    // ws layout
    ushort* uhi = (ushort*)d_ws;                                   // 32 KB
    ushort* ulo = (ushort*)((char*)d_ws + 32768);                  // 32 KB
    float*  ufp = (float*)((char*)d_ws + 65536);                   // 64 KB
    int*    cnd = (int*)((char*)d_ws + 131072);                    // 32 KB
    const size_t off_part = 131072 + 32768;
    unsigned long long* part =
        (unsigned long long*)((char*)d_ws + off_part);

    size_t avail = (ws_size > off_part) ? (ws_size - off_part) : 0;
    long maxblk = (long)(avail / ((size_t)BB * TOPK * 8));
    if (maxblk < 1) maxblk = 1;
    int chunk = 1024;                       // multiple of TI
    int nblk = (NITEMS + chunk - 1) / chunk;
    if (nblk > maxblk) {
        long c = (NITEMS + maxblk - 1) / maxblk;
        chunk = (int)((c + TI - 1) / TI) * TI;
        nblk = (NITEMS + chunk - 1) / chunk;
    }

    user_kernel<<<BB, DD, 0, stream>>>(profile, context, item_idx, iv,
                                       Wp, Wc, Wu, bu, uhi, ulo, ufp);
    score_kernel<<<nblk, SCORE_THREADS, 0, stream>>>(iv, uhi, ulo, part,
                                                     chunk, nblk);
    merge_kernel<<<BB, 256, 0, stream>>>(part, cnd, nblk);
    rescore_kernel<<<BB, DD, 0, stream>>>(iv, ufp, cnd, (int*)d_out);
}

// Round 5
// 263.498 us; speedup vs baseline: 5.2379x; 4.4534x over previous
//
#include <hip/hip_runtime.h>
#include <hip/hip_bf16.h>
#include <stdint.h>

#define BB   256
#define DD   64
#define LLEN 50
#define PDIM 10
#define CDIM 8
#define NITEMS 1000000
#define TOPK 20
#define TI   128            // items per LDS tile
#define SCORE_THREADS 512
#define SSTRIDE 64          // sample stride for threshold estimation
#define NSAMP (NITEMS / SSTRIDE)   // 15625
#define CAP  7168           // survivor capacity per user (mean ~1300)
#define MARGIN 3e-4f        // covers |approx - exact| (<~8e-5) with slack

typedef short v8s __attribute__((ext_vector_type(8)));   // 8 bf16 (4 VGPR)
typedef float v4f __attribute__((ext_vector_type(4)));   // MFMA acc

// float -> bf16 bits, round-to-nearest-even
__device__ __forceinline__ uint32_t f2bf_rne(float f) {
    uint32_t u = __float_as_uint(f);
    return (u + 0x7FFFu + ((u >> 16) & 1u)) >> 16;
}

// ---- sortable key: larger key == better (higher score, then lower index) ----
__device__ __forceinline__ unsigned long long pack_key(float s, unsigned n) {
    unsigned sb = __float_as_uint(s);
    sb = (sb & 0x80000000u) ? ~sb : (sb | 0x80000000u);
    return ((unsigned long long)sb << 32) | (unsigned)(~n);
}

__device__ __forceinline__ float unpack_score(unsigned sb) {
    unsigned orig = (sb & 0x80000000u) ? (sb & 0x7FFFFFFFu) : ~sb;
    return __uint_as_float(orig);
}

__device__ __forceinline__ unsigned long long shfl_xor_u64(unsigned long long x, int m) {
    unsigned lo = (unsigned)x, hi = (unsigned)(x >> 32);
    lo = __shfl_xor(lo, m);
    hi = __shfl_xor(hi, m);
    return ((unsigned long long)hi << 32) | lo;
}

// ================= Phase A: user tower -> fp32 + bf16 hi/lo user vectors =====
__global__ __launch_bounds__(64) void user_kernel(
        const int* __restrict__ profile,      // [B,10]
        const int* __restrict__ context,      // [B,50,8]
        const int* __restrict__ item_idx,     // [B,50]
        const float* __restrict__ iv,         // [N,64]
        const float* __restrict__ Wp,         // [10,64]
        const float* __restrict__ Wc,         // [8,64]
        const float* __restrict__ Wu,         // [64,64]
        const float* __restrict__ bu,         // [64]
        ushort* __restrict__ uhi,             // [256,64] bf16 bits
        ushort* __restrict__ ulo,             // [256,64] bf16 bits
        float*  __restrict__ ufp)             // [256,64] fp32
{
    const int b = blockIdx.x;
    const int d = threadIdx.x;   // 0..63

    float p = 0.f;
    #pragma unroll
    for (int j = 0; j < PDIM; ++j)
        p += (float)profile[b * PDIM + j] * Wp[j * DD + d];

    float c = 0.f;
    #pragma unroll
    for (int j = 0; j < CDIM; ++j) {
        int s = 0;
        for (int l = 0; l < LLEN; ++l)
            s += context[(b * LLEN + l) * CDIM + j];
        c += ((float)s * (1.f / (float)LLEN)) * Wc[j * DD + d];
    }

    float si = 0.f;
    for (int l = 0; l < LLEN; ++l) {
        size_t n = (size_t)item_idx[b * LLEN + l];
        si += iv[n * DD + d];
    }
    si *= (1.f / (float)LLEN);

    __shared__ float sh[DD];
    sh[d] = p + c + si;
    __syncthreads();

    float acc = bu[d];
    #pragma unroll
    for (int dd = 0; dd < DD; ++dd)
        acc = fmaf(sh[dd], Wu[dd * DD + d], acc);

    float val = tanhf(acc);
    ufp[b * DD + d] = val;
    uint32_t hb = f2bf_rne(val);
    float hf = __uint_as_float(hb << 16);
    uint32_t lb = f2bf_rne(val - hf);
    uhi[b * DD + d] = (ushort)hb;
    ulo[b * DD + d] = (ushort)lb;
}

// ====== Phase A2: per-user threshold from exact fp32 sample (1/64 items) =====
// tau[b] = (20th best of sample) - MARGIN. Safe: true-20th >= sample-20th.
// Per-thread top-3 then 20 rounds of block max-extract (union 20th <= sample
// 20th, so tau only gets looser -> still safe). Also zeroes cnt[b].
__global__ __launch_bounds__(256) void tau_kernel(
        const float* __restrict__ iv,    // [N,64]
        const float* __restrict__ ufp,   // [256,64]
        float* __restrict__ tau,         // [256]
        int*   __restrict__ cnt)         // [256*64] padded counters
{
    const int b = blockIdx.x;
    const int t = threadIdx.x;

    __shared__ float uS[DD];
    __shared__ unsigned long long lc[256 * 3];
    __shared__ unsigned long long wm[4];
    if (t < DD) uS[t] = ufp[b * DD + t];
    if (t == 0) cnt[b * 64] = 0;
    __syncthreads();

    unsigned long long b0 = 0, b1 = 0, b2 = 0;   // top-3 descending
    for (int s = t; s < NSAMP; s += 256) {
        long item = (long)s * SSTRIDE;
        const float4* row = (const float4*)(iv + (size_t)item * DD);
        float acc = 0.f;
        #pragma unroll
        for (int q = 0; q < 16; ++q) {
            float4 v = row[q];
            acc = fmaf(v.x, uS[4 * q + 0], acc);
            acc = fmaf(v.y, uS[4 * q + 1], acc);
            acc = fmaf(v.z, uS[4 * q + 2], acc);
            acc = fmaf(v.w, uS[4 * q + 3], acc);
        }
        unsigned long long key = pack_key(acc, (unsigned)item);
        if (key > b2) {
            if (key > b0)      { b2 = b1; b1 = b0; b0 = key; }
            else if (key > b1) { b2 = b1; b1 = key; }
            else               { b2 = key; }
        }
    }
    lc[t * 3 + 0] = b0; lc[t * 3 + 1] = b1; lc[t * 3 + 2] = b2;
    __syncthreads();

    int own = 0;
    for (int round = 0; round < TOPK; ++round) {
        unsigned long long v = (own < 3) ? lc[t * 3 + own] : 0ull;
        unsigned long long m = v;
        #pragma unroll
        for (int s = 32; s > 0; s >>= 1) {
            unsigned long long o = shfl_xor_u64(m, s);
            m = (o > m) ? o : m;
        }
        if ((t & 63) == 0) wm[t >> 6] = m;
        __syncthreads();
        unsigned long long g01 = (wm[0] > wm[1]) ? wm[0] : wm[1];
        unsigned long long g23 = (wm[2] > wm[3]) ? wm[2] : wm[3];
        unsigned long long g = (g01 > g23) ? g01 : g23;
        if (v == g && v != 0ull) own++;
        if (round == TOPK - 1 && t == 0)
            tau[b] = unpack_score((unsigned)(g >> 32)) - MARGIN;
        __syncthreads();
    }
}

// ============ Phase B: MFMA scoring + threshold filter (NO top-k state) ======
// 512 threads = 8 waves. Wave w owns users [32w,32w+32) (two 16-user B-tiles).
// LDS frag layout (VERIFIED R2/R4): frag f=2*ms+ks at words [f*256,+256),
// word = f*256 + 4*slot + j, slot=(item&15)+16*q, word j = dims 32ks+8q+{2j,2j+1}.
// Staging: wave w fills frags (ms=w, ks=0/1): lane l -> item 16w+(l&15),
// q=l>>4 -> slot==l -> 16B write at frag_base+16*l (2-way bank = free).
__global__ __launch_bounds__(SCORE_THREADS, 4) void filter_kernel(
        const float*  __restrict__ iv,     // [N,64]
        const ushort* __restrict__ uhi,    // [256,64]
        const ushort* __restrict__ ulo,    // [256,64]
        const float*  __restrict__ tau,    // [256]
        int* __restrict__ cnt,             // [256*64] padded
        int* __restrict__ surv,            // [256][CAP]
        int chunk)
{
    __shared__ uint32_t lds[2][2][4096];   // [buf][hi/lo][16KB] = 64 KB

    const int t    = threadIdx.x;
    const int w    = t >> 6;
    const int lane = t & 63;
    const int blk  = blockIdx.x;
    const long base = (long)blk * (long)chunk;

    // ---- user B-fragments (col=lane&15=user, k=32ks+8*(lane>>4)+e) ----
    const int ua = 32 * w + (lane & 15);
    const int ub = ua + 16;
    v8s uhA[2], ulA[2], uhB[2], ulB[2];
    #pragma unroll
    for (int ks = 0; ks < 2; ++ks) {
        int kk = 32 * ks + 8 * (lane >> 4);
        uhA[ks] = *(const v8s*)(uhi + ua * DD + kk);
        ulA[ks] = *(const v8s*)(ulo + ua * DD + kk);
        uhB[ks] = *(const v8s*)(uhi + ub * DD + kk);
        ulB[ks] = *(const v8s*)(ulo + ub * DD + kk);
    }
    const float tA = tau[ua];
    const float tB = tau[ub];

    long nitems_blk = (long)NITEMS - base;
    if (nitems_blk > chunk) nitems_blk = chunk;
    const int ntiles = (int)((nitems_blk + TI - 1) / TI);

    // ---- staging regs: item 16w+(l&15), dims 32ks+8*(l>>4)+0..7 ----
    float4 st[4];
    const long my_item_off = 16 * w + (lane & 15);
    const int  my_dim0     = 8 * (lane >> 4);

    auto stage_issue = [&](long tb) {
        long item = base + tb + my_item_off;
        if (item < (long)NITEMS) {
            const float* rowp = iv + (size_t)item * DD + my_dim0;
            #pragma unroll
            for (int ks = 0; ks < 2; ++ks) {
                const float4* p = (const float4*)(rowp + 32 * ks);
                st[2 * ks]     = p[0];
                st[2 * ks + 1] = p[1];
            }
        } else {
            #pragma unroll
            for (int r = 0; r < 4; ++r) st[r] = make_float4(0.f, 0.f, 0.f, 0.f);
        }
    };
    auto stage_write = [&](int buf) {
        #pragma unroll
        for (int ks = 0; ks < 2; ++ks) {
            float f[8] = {st[2*ks].x, st[2*ks].y, st[2*ks].z, st[2*ks].w,
                          st[2*ks+1].x, st[2*ks+1].y, st[2*ks+1].z, st[2*ks+1].w};
            uint32_t hw[4], lw[4];
            #pragma unroll
            for (int j = 0; j < 4; ++j) {
                uint32_t h0 = f2bf_rne(f[2 * j]);        // RNE split (verified)
                uint32_t h1 = f2bf_rne(f[2 * j + 1]);
                float hf0 = __uint_as_float(h0 << 16);
                float hf1 = __uint_as_float(h1 << 16);
                uint32_t l0 = f2bf_rne(f[2 * j]     - hf0);
                uint32_t l1 = f2bf_rne(f[2 * j + 1] - hf1);
                hw[j] = h0 | (h1 << 16);
                lw[j] = l0 | (l1 << 16);
            }
            int fr = 2 * w + ks;
            int wd = fr * 256 + 4 * lane;
            *(uint4*)&lds[buf][0][wd] = make_uint4(hw[0], hw[1], hw[2], hw[3]);
            *(uint4*)&lds[buf][1][wd] = make_uint4(lw[0], lw[1], lw[2], lw[3]);
        }
    };

    auto emit = [&](int user, float s, long idx) {
        if (idx < (long)NITEMS) {
            int pos = atomicAdd(&cnt[user * 64], 1);
            if (pos < CAP) surv[(size_t)user * CAP + pos] = (int)idx;
        }
    };

    stage_issue(0);
    stage_write(0);
    __syncthreads();

    for (int tt = 0; tt < ntiles; ++tt) {
        const int buf = tt & 1;
        if (tt + 1 < ntiles) stage_issue((long)(tt + 1) * TI);

        const long ibase = base + (long)tt * TI;
        #pragma unroll
        for (int ms = 0; ms < 8; ++ms) {
            v4f accA = {0.f, 0.f, 0.f, 0.f};
            v4f accB = {0.f, 0.f, 0.f, 0.f};
            #pragma unroll
            for (int ks = 0; ks < 2; ++ks) {
                int bidx = ((ms * 2 + ks) * 64 + lane) * 4;
                v8s ah = *(const v8s*)&lds[buf][0][bidx];
                v8s al = *(const v8s*)&lds[buf][1][bidx];
                accA = __builtin_amdgcn_mfma_f32_16x16x32_bf16(ah, uhA[ks], accA, 0, 0, 0);
                accB = __builtin_amdgcn_mfma_f32_16x16x32_bf16(ah, uhB[ks], accB, 0, 0, 0);
                accA = __builtin_amdgcn_mfma_f32_16x16x32_bf16(al, uhA[ks], accA, 0, 0, 0);
                accB = __builtin_amdgcn_mfma_f32_16x16x32_bf16(al, uhB[ks], accB, 0, 0, 0);
                accA = __builtin_amdgcn_mfma_f32_16x16x32_bf16(ah, ulA[ks], accA, 0, 0, 0);
                accB = __builtin_amdgcn_mfma_f32_16x16x32_bf16(ah, ulB[ks], accB, 0, 0, 0);
            }
            // D layout: col=lane&15 (user), row=(lane>>4)*4+reg (item)
            long irow = ibase + ms * 16 + (lane >> 4) * 4;

            float mA = fmaxf(fmaxf(accA[0], accA[1]), fmaxf(accA[2], accA[3]));
            if (mA >= tA) {
                #pragma unroll
                for (int r = 0; r < 4; ++r)
                    if (accA[r] >= tA) emit(ua, accA[r], irow + r);
            }
            float mB = fmaxf(fmaxf(accB[0], accB[1]), fmaxf(accB[2], accB[3]));
            if (mB >= tB) {
                #pragma unroll
                for (int r = 0; r < 4; ++r)
                    if (accB[r] >= tB) emit(ub, accB[r], irow + r);
            }
        }

        if (tt + 1 < ntiles) stage_write(buf ^ 1);
        __syncthreads();
    }
}

// ====== Phase C: exact fp32 rescore of survivors -> exact top-20 indices =====
__global__ __launch_bounds__(256) void rescore_kernel(
        const float* __restrict__ iv,    // [N,64]
        const float* __restrict__ ufp,   // [256,64]
        const int*   __restrict__ cnt,   // [256*64]
        const int*   __restrict__ surv,  // [256][CAP]
        int* __restrict__ out)           // [256,20]
{
    const int b = blockIdx.x;
    const int t = threadIdx.x;

    __shared__ float uS[DD];
    __shared__ unsigned long long keys[CAP];     // 56 KB
    __shared__ unsigned long long wm[4];
    if (t < DD) uS[t] = ufp[b * DD + t];
    __syncthreads();

    int n = cnt[b * 64];
    if (n > CAP) n = CAP;

    for (int i = t; i < n; i += 256) {
        int idx = surv[(size_t)b * CAP + i];
        const float4* row = (const float4*)(iv + (size_t)idx * DD);
        float acc = 0.f;
        #pragma unroll
        for (int q = 0; q < 16; ++q) {
            float4 v = row[q];
            acc = fmaf(v.x, uS[4 * q + 0], acc);
            acc = fmaf(v.y, uS[4 * q + 1], acc);
            acc = fmaf(v.z, uS[4 * q + 2], acc);
            acc = fmaf(v.w, uS[4 * q + 3], acc);
        }
        keys[i] = pack_key(acc, (unsigned)idx);
    }
    __syncthreads();

    for (int round = 0; round < TOPK; ++round) {
        unsigned long long lm = 0ull;
        int lslot = -1;
        for (int i = t; i < n; i += 256) {
            unsigned long long k = keys[i];
            if (k > lm) { lm = k; lslot = i; }
        }
        unsigned long long m = lm;
        #pragma unroll
        for (int s = 32; s > 0; s >>= 1) {
            unsigned long long o = shfl_xor_u64(m, s);
            m = (o > m) ? o : m;
        }
        if ((t & 63) == 0) wm[t >> 6] = m;
        __syncthreads();
        unsigned long long g01 = (wm[0] > wm[1]) ? wm[0] : wm[1];
        unsigned long long g23 = (wm[2] > wm[3]) ? wm[2] : wm[3];
        unsigned long long g = (g01 > g23) ? g01 : g23;
        if (lm == g && g != 0ull) keys[lslot] = 0ull;   // unique keys
        if (t == 0)
            out[b * TOPK + round] = (int)(~(unsigned)(g & 0xFFFFFFFFull));
        __syncthreads();
    }
}

// =============================================================================
extern "C" void kernel_launch(void* const* d_in, const int* in_sizes, int n_in,
                              void* d_out, int out_size, void* d_ws, size_t ws_size,
                              hipStream_t stream) {
    const int*   profile  = (const int*)d_in[0];
    const int*   context  = (const int*)d_in[1];
    const int*   item_idx = (const int*)d_in[2];
    const float* iv       = (const float*)d_in[3];
    const float* Wp       = (const float*)d_in[4];
    const float* Wc       = (const float*)d_in[5];
    const float* Wu       = (const float*)d_in[6];
    const float* bu       = (const float*)d_in[7];

    // ws layout (total ~7.6 MB; R-series runs confirmed ws >= 40 MB)
    char* wsb = (char*)d_ws;
    ushort* uhi = (ushort*)(wsb);                      // 32 KB
    ushort* ulo = (ushort*)(wsb + 32768);              // 32 KB
    float*  ufp = (float*) (wsb + 65536);              // 64 KB
    float*  tau = (float*) (wsb + 131072);             // 1 KB
    int*    cnt = (int*)   (wsb + 132096);             // 64 KB (stride-64 pad)
    int*    surv= (int*)   (wsb + 132096 + 65536);     // 256*CAP*4 = 7.0 MB

    const int chunk = 1024;                            // multiple of TI
    const int nblk = (NITEMS + chunk - 1) / chunk;     // 977

    user_kernel<<<BB, DD, 0, stream>>>(profile, context, item_idx, iv,
                                       Wp, Wc, Wu, bu, uhi, ulo, ufp);
    tau_kernel<<<BB, 256, 0, stream>>>(iv, ufp, tau, cnt);
    filter_kernel<<<nblk, SCORE_THREADS, 0, stream>>>(iv, uhi, ulo, tau,
                                                      cnt, surv, chunk);
    rescore_kernel<<<BB, 256, 0, stream>>>(iv, ufp, cnt, surv, (int*)d_out);
}